// Round 12
// baseline (809.040 us; speedup 1.0000x reference)
//
#include <hip/hip_runtime.h>
#include <hip/hip_cooperative_groups.h>
#include <stdint.h>

namespace cg = cooperative_groups;

// Problem constants (fixed by setup_inputs)
#define N_IMG 4
#define E_DIM 16
#define H_DIM 768
#define W_DIM 768
#define P_PIX (H_DIM * W_DIM)   // 589824 pixels per image
#define C_CL 32

#define DELTA_VAR 0.5f
#define DELTA_DIST 2.0f
#define GAMMA_W 0.001f
#define EPS_F 1e-12f

// Workspace layout (floats):
//   [0,    2048): sums   [N][C][E]        (c*16+e)
//   [2048, 2176): counts [N][C]
//   [2176, 4480): hinge partials (fused: [N][256]; legacy: [N][288])
//   [4480, ...) : pass1 per-block partials (fused: [N][256][544]; legacy [N][576][544])
#define WS_SUMS 0
#define WS_CNT 2048
#define WS_HINGE 2176
#define WS_HP 2176
#define WS_PART 4480
#define PART_STRIDE 544   // 512 sums + 32 counts per block

// Fused geometry: 1024 blocks = 4 img x 256 blocks; 2304 px/block.
#define FB_PER_IMG 256
#define F_TILES 18               // per wave: 576 px = 18 tiles of 32
#define NPART_F (N_IMG * FB_PER_IMG * PART_STRIDE)

// Legacy geometry (fallback path, HW-verified rounds 4/7/10/11)
#define P1_BLOCKS 576
#define P1_TILES 8
#define PX2 2048
#define BLOCKS2_X (P_PIX / PX2) // 288
#define NPART_L (N_IMG * P1_BLOCKS * PART_STRIDE)

using bf16x8 = __attribute__((ext_vector_type(8))) short;
using f32x4 = __attribute__((ext_vector_type(4))) float;

__device__ __forceinline__ void gatomic_add(float* p, float v) {
#if defined(__HIP_DEVICE_COMPILE__)
  unsafeAtomicAdd(p, v);
#else
  atomicAdd(p, v);
#endif
}

// ============================ FUSED KERNEL ============================
// All four phases in one cooperative dispatch for (a) full per-dispatch PMC
// attribution -- since r7 every kernel sat below the top-5 fill cutoff and
// three pass2 rewrites were unexplainably neutral -- and (b) no launch gaps.
__global__ __launch_bounds__(256, 4) void fused(const float* __restrict__ input,
                                                const int* __restrict__ target,
                                                float* __restrict__ ws,
                                                float* __restrict__ out) {
  __shared__ float s_red[4][2][4][64];  // 8 KB  (phase A)
  __shared__ float s_cnt[4][2][16];     // 512 B (phase A)
  __shared__ float s_r8[8][32];         // 1 KB  (phase B)
  __shared__ float s_meanT[E_DIM][C_CL];// 2 KB  (phase C)
  __shared__ float s_icnt[C_CL];        // 128 B (phase C)
  __shared__ float s_part[4];           // 16 B  (phase C)
  __shared__ float s_fm[N_IMG * C_CL * E_DIM];  // 8 KB (phase D)
  __shared__ float s_red2[256];         // 1 KB  (phase D)

  const int tid = threadIdx.x;
  const int bid = blockIdx.x;
  const int n = bid >> 8, blk = bid & 255;

  // -------- Phase A: MFMA segment-sum (HW-verified inner loop) --------
  {
    const int wv = tid >> 6, l = tid & 63;
    const int g = l >> 4, cl = l & 15;
    const int wid = blk * 4 + wv;             // [0,1024) per image
    const int base = wid * 576 + g * 8;
    const float* rowp = input + ((size_t)n * E_DIM + cl) * P_PIX;
    const int* tgt = target + (size_t)n * P_PIX;

    f32x4 acc0 = {0.f, 0.f, 0.f, 0.f}, acc1 = {0.f, 0.f, 0.f, 0.f};
    f32x4 cnt0 = {0.f, 0.f, 0.f, 0.f}, cnt1 = {0.f, 0.f, 0.f, 0.f};
    const short ONE = (short)0x3F80;
    const bf16x8 ones = {ONE, ONE, ONE, ONE, ONE, ONE, ONE, ONE};

    float4 va = *reinterpret_cast<const float4*>(rowp + base);
    float4 vb = *reinterpret_cast<const float4*>(rowp + base + 4);
    int4 la = *reinterpret_cast<const int4*>(tgt + base);
    int4 lb = *reinterpret_cast<const int4*>(tgt + base + 4);

    for (int t = 0; t < F_TILES; ++t) {
      const float4 cva = va, cvb = vb;
      const int4 cla = la, clb = lb;
      if (t + 1 < F_TILES) {
        const int p = base + (t + 1) * 32;
        va = *reinterpret_cast<const float4*>(rowp + p);
        vb = *reinterpret_cast<const float4*>(rowp + p + 4);
        la = *reinterpret_cast<const int4*>(tgt + p);
        lb = *reinterpret_cast<const int4*>(tgt + p + 4);
      }
      float ff[8];
      ff[0] = cva.x; ff[1] = cva.y; ff[2] = cva.z; ff[3] = cva.w;
      ff[4] = cvb.x; ff[5] = cvb.y; ff[6] = cvb.z; ff[7] = cvb.w;
      int lab[8];
      lab[0] = cla.x; lab[1] = cla.y; lab[2] = cla.z; lab[3] = cla.w;
      lab[4] = clb.x; lab[5] = clb.y; lab[6] = clb.z; lab[7] = clb.w;

      union BF { uint32_t w[4]; bf16x8 v; } Ahi, Alo, B0, B1;
#pragma unroll
      for (int q = 0; q < 4; ++q) {
        const uint32_t u0 = __float_as_uint(ff[2 * q]);
        const uint32_t u1 = __float_as_uint(ff[2 * q + 1]);
        Ahi.w[q] = (u0 >> 16) | (u1 & 0xFFFF0000u);
        const float r0 = ff[2 * q] - __uint_as_float(u0 & 0xFFFF0000u);
        const float r1 = ff[2 * q + 1] - __uint_as_float(u1 & 0xFFFF0000u);
        Alo.w[q] = (__float_as_uint(r0) >> 16) | (__float_as_uint(r1) & 0xFFFF0000u);
        B0.w[q] = ((lab[2 * q] == cl) ? 0x3F80u : 0u) |
                  ((lab[2 * q + 1] == cl) ? 0x3F800000u : 0u);
        B1.w[q] = ((lab[2 * q] == cl + 16) ? 0x3F80u : 0u) |
                  ((lab[2 * q + 1] == cl + 16) ? 0x3F800000u : 0u);
      }
      acc0 = __builtin_amdgcn_mfma_f32_16x16x32_bf16(Ahi.v, B0.v, acc0, 0, 0, 0);
      acc0 = __builtin_amdgcn_mfma_f32_16x16x32_bf16(Alo.v, B0.v, acc0, 0, 0, 0);
      acc1 = __builtin_amdgcn_mfma_f32_16x16x32_bf16(Ahi.v, B1.v, acc1, 0, 0, 0);
      acc1 = __builtin_amdgcn_mfma_f32_16x16x32_bf16(Alo.v, B1.v, acc1, 0, 0, 0);
      cnt0 = __builtin_amdgcn_mfma_f32_16x16x32_bf16(ones, B0.v, cnt0, 0, 0, 0);
      cnt1 = __builtin_amdgcn_mfma_f32_16x16x32_bf16(ones, B1.v, cnt1, 0, 0, 0);
    }

#pragma unroll
    for (int r = 0; r < 4; ++r) {
      s_red[wv][0][r][l] = acc0[r];
      s_red[wv][1][r][l] = acc1[r];
    }
    if (g == 0) {
      s_cnt[wv][0][cl] = cnt0[0];
      s_cnt[wv][1][cl] = cnt1[0];
    }
    __syncthreads();

    float* pbase = ws + WS_PART + (size_t)(n * FB_PER_IMG + blk) * PART_STRIDE;
#pragma unroll
    for (int i = tid; i < 512; i += 256) {
      const int h = i >> 8, r = (i >> 6) & 3, ll = i & 63;
      const float v = s_red[0][h][r][ll] + s_red[1][h][r][ll] +
                      s_red[2][h][r][ll] + s_red[3][h][r][ll];
      const int c = (ll & 15) + 16 * h;
      const int e = (ll >> 4) * 4 + r;
      pbase[c * E_DIM + e] = v;
    }
    if (tid < C_CL) {
      const int h = tid >> 4, c16 = tid & 15;
      pbase[512 + tid] = s_cnt[0][h][c16] + s_cnt[1][h][c16] +
                         s_cnt[2][h][c16] + s_cnt[3][h][c16];
    }
  }
  __threadfence();
  cg::this_grid().sync();

  // -------- Phase B: reduce partials (blocks 0..67) --------
  if (bid < 68) {
    const int nn = bid / 17, ib = bid - nn * 17;
    const int bs = tid >> 5, il = tid & 31;
    const int i = ib * 32 + il;  // [0,544)
    const float* part = ws + WS_PART + (size_t)nn * FB_PER_IMG * PART_STRIDE;
    float acc = 0.f;
#pragma unroll 8
    for (int b = bs; b < FB_PER_IMG; b += 8) acc += part[b * PART_STRIDE + i];
    s_r8[bs][il] = acc;
    __syncthreads();
    if (tid < 32) {
      const int ii = ib * 32 + tid;
      float t = s_r8[0][tid] + s_r8[1][tid] + s_r8[2][tid] + s_r8[3][tid] +
                s_r8[4][tid] + s_r8[5][tid] + s_r8[6][tid] + s_r8[7][tid];
      if (ii < 512)
        ws[WS_SUMS + nn * 512 + ii] = t;
      else
        ws[WS_CNT + nn * C_CL + (ii - 512)] = t;
    }
  }
  __threadfence();
  cg::this_grid().sync();

  // -------- Phase C: hinge (linear e-outer streaming, r11 structure) --------
  {
    const float* gsum = ws + WS_SUMS + n * 512;
    const float* gcnt = ws + WS_CNT + n * C_CL;
    for (int i = tid; i < 512; i += 256) {
      const int c = i >> 4, e = i & 15;
      s_meanT[e][c] = gsum[i] / gcnt[c];
    }
    if (tid < C_CL) s_icnt[tid] = 1.0f / gcnt[tid];
    __syncthreads();

    const int base2 = blk * 2304;
    const float* inp_n = input + (size_t)n * E_DIM * P_PIX;
    const int* tgt_n = target + (size_t)n * P_PIX;
    float acc = 0.f;

    {  // two full 1024-px windows
      const int pA = base2 + tid * 4;
      const int pB = pA + 1024;
      const int4 labA = *reinterpret_cast<const int4*>(tgt_n + pA);
      const int4 labB = *reinterpret_cast<const int4*>(tgt_n + pB);
      float aA0 = 0.f, aA1 = 0.f, aA2 = 0.f, aA3 = 0.f;
      float aB0 = 0.f, aB1 = 0.f, aB2 = 0.f, aB3 = 0.f;
#pragma unroll
      for (int e = 0; e < E_DIM; ++e) {
        const float* row = inp_n + (size_t)e * P_PIX;
        const float4 vA = *reinterpret_cast<const float4*>(row + pA);
        const float4 vB = *reinterpret_cast<const float4*>(row + pB);
        float d;
        d = vA.x - s_meanT[e][labA.x]; aA0 += d * d;
        d = vA.y - s_meanT[e][labA.y]; aA1 += d * d;
        d = vA.z - s_meanT[e][labA.z]; aA2 += d * d;
        d = vA.w - s_meanT[e][labA.w]; aA3 += d * d;
        d = vB.x - s_meanT[e][labB.x]; aB0 += d * d;
        d = vB.y - s_meanT[e][labB.y]; aB1 += d * d;
        d = vB.z - s_meanT[e][labB.z]; aB2 += d * d;
        d = vB.w - s_meanT[e][labB.w]; aB3 += d * d;
      }
      float dd, h;
      dd = sqrtf(fmaxf(aA0, EPS_F)); h = fmaxf(dd - DELTA_VAR, 0.f);
      acc += h * h * s_icnt[labA.x];
      dd = sqrtf(fmaxf(aA1, EPS_F)); h = fmaxf(dd - DELTA_VAR, 0.f);
      acc += h * h * s_icnt[labA.y];
      dd = sqrtf(fmaxf(aA2, EPS_F)); h = fmaxf(dd - DELTA_VAR, 0.f);
      acc += h * h * s_icnt[labA.z];
      dd = sqrtf(fmaxf(aA3, EPS_F)); h = fmaxf(dd - DELTA_VAR, 0.f);
      acc += h * h * s_icnt[labA.w];
      dd = sqrtf(fmaxf(aB0, EPS_F)); h = fmaxf(dd - DELTA_VAR, 0.f);
      acc += h * h * s_icnt[labB.x];
      dd = sqrtf(fmaxf(aB1, EPS_F)); h = fmaxf(dd - DELTA_VAR, 0.f);
      acc += h * h * s_icnt[labB.y];
      dd = sqrtf(fmaxf(aB2, EPS_F)); h = fmaxf(dd - DELTA_VAR, 0.f);
      acc += h * h * s_icnt[labB.z];
      dd = sqrtf(fmaxf(aB3, EPS_F)); h = fmaxf(dd - DELTA_VAR, 0.f);
      acc += h * h * s_icnt[labB.w];
    }
    if (tid < 64) {  // 256-px tail window
      const int pT = base2 + 2048 + tid * 4;
      const int4 lab = *reinterpret_cast<const int4*>(tgt_n + pT);
      float a0 = 0.f, a1 = 0.f, a2 = 0.f, a3 = 0.f;
#pragma unroll
      for (int e = 0; e < E_DIM; ++e) {
        const float* row = inp_n + (size_t)e * P_PIX;
        const float4 v = *reinterpret_cast<const float4*>(row + pT);
        float d;
        d = v.x - s_meanT[e][lab.x]; a0 += d * d;
        d = v.y - s_meanT[e][lab.y]; a1 += d * d;
        d = v.z - s_meanT[e][lab.z]; a2 += d * d;
        d = v.w - s_meanT[e][lab.w]; a3 += d * d;
      }
      float dd, h;
      dd = sqrtf(fmaxf(a0, EPS_F)); h = fmaxf(dd - DELTA_VAR, 0.f);
      acc += h * h * s_icnt[lab.x];
      dd = sqrtf(fmaxf(a1, EPS_F)); h = fmaxf(dd - DELTA_VAR, 0.f);
      acc += h * h * s_icnt[lab.y];
      dd = sqrtf(fmaxf(a2, EPS_F)); h = fmaxf(dd - DELTA_VAR, 0.f);
      acc += h * h * s_icnt[lab.z];
      dd = sqrtf(fmaxf(a3, EPS_F)); h = fmaxf(dd - DELTA_VAR, 0.f);
      acc += h * h * s_icnt[lab.w];
    }
#pragma unroll
    for (int off = 32; off > 0; off >>= 1) acc += __shfl_down(acc, off);
    if ((tid & 63) == 0) s_part[tid >> 6] = acc;
    __syncthreads();
    if (tid == 0)
      ws[WS_HP + n * FB_PER_IMG + blk] =
          s_part[0] + s_part[1] + s_part[2] + s_part[3];
  }
  __threadfence();
  cg::this_grid().sync();

  // -------- Phase D: finalize (block 0) --------
  if (bid == 0) {
    for (int i = tid; i < N_IMG * C_CL * E_DIM; i += 256) {
      s_fm[i] = ws[WS_SUMS + i] / ws[WS_CNT + (i >> 4)];
    }
    __syncthreads();
    float acc = 0.f;
    for (int i = tid; i < N_IMG * FB_PER_IMG; i += 256)
      acc += ws[WS_HP + i] * (1.0f / C_CL);
    for (int i = tid; i < N_IMG * C_CL; i += 256) {
      float nrm2 = 0.f;
      const float* m = s_fm + i * E_DIM;
#pragma unroll
      for (int e = 0; e < E_DIM; ++e) nrm2 += m[e] * m[e];
      acc += GAMMA_W * sqrtf(fmaxf(nrm2, EPS_F)) * (1.0f / C_CL);
    }
    for (int t = tid; t < N_IMG * C_CL * C_CL; t += 256) {
      const int nn = t / (C_CL * C_CL);
      const int r = t - nn * C_CL * C_CL;
      const int a = r >> 5, b = r & 31;
      if (a != b) {
        const float* ma = s_fm + (nn * C_CL + a) * E_DIM;
        const float* mb = s_fm + (nn * C_CL + b) * E_DIM;
        float d2 = 0.f;
#pragma unroll
        for (int e = 0; e < E_DIM; ++e) {
          const float df = ma[e] - mb[e];
          d2 += df * df;
        }
        const float dist = sqrtf(fmaxf(d2, EPS_F));
        const float hd = fmaxf(2.f * DELTA_DIST - dist, 0.f);
        acc += hd * hd * (1.0f / (C_CL * (C_CL - 1)));
      }
    }
    s_red2[tid] = acc;
    __syncthreads();
    for (int s = 128; s > 0; s >>= 1) {
      if (tid < s) s_red2[tid] += s_red2[tid + s];
      __syncthreads();
    }
    if (tid == 0) out[0] = s_red2[0] * (1.0f / N_IMG);
  }
}

// ===================== LEGACY PATH (HW-verified fallback) =====================
__global__ __launch_bounds__(256) void pass1(const float* __restrict__ input,
                                             const int* __restrict__ target,
                                             float* __restrict__ ws,
                                             int partmode) {
  __shared__ float s_red[4][2][4][64];
  __shared__ float s_cnt[4][2][16];
  const int tid = threadIdx.x;
  const int wv = tid >> 6, l = tid & 63;
  const int g = l >> 4, cl = l & 15;
  const int n = blockIdx.y;
  const int wid = blockIdx.x * 4 + wv;
  const int base = wid * (P1_TILES * 32) + g * 8;
  const float* rowp = input + ((size_t)n * E_DIM + cl) * P_PIX;
  const int* tgt = target + (size_t)n * P_PIX;

  f32x4 acc0 = {0.f, 0.f, 0.f, 0.f}, acc1 = {0.f, 0.f, 0.f, 0.f};
  f32x4 cnt0 = {0.f, 0.f, 0.f, 0.f}, cnt1 = {0.f, 0.f, 0.f, 0.f};
  const short ONE = (short)0x3F80;
  const bf16x8 ones = {ONE, ONE, ONE, ONE, ONE, ONE, ONE, ONE};

  float4 va = *reinterpret_cast<const float4*>(rowp + base);
  float4 vb = *reinterpret_cast<const float4*>(rowp + base + 4);
  int4 la = *reinterpret_cast<const int4*>(tgt + base);
  int4 lb = *reinterpret_cast<const int4*>(tgt + base + 4);

  for (int t = 0; t < P1_TILES; ++t) {
    const float4 cva = va, cvb = vb;
    const int4 cla = la, clb = lb;
    if (t + 1 < P1_TILES) {
      const int p = base + (t + 1) * 32;
      va = *reinterpret_cast<const float4*>(rowp + p);
      vb = *reinterpret_cast<const float4*>(rowp + p + 4);
      la = *reinterpret_cast<const int4*>(tgt + p);
      lb = *reinterpret_cast<const int4*>(tgt + p + 4);
    }
    float ff[8];
    ff[0] = cva.x; ff[1] = cva.y; ff[2] = cva.z; ff[3] = cva.w;
    ff[4] = cvb.x; ff[5] = cvb.y; ff[6] = cvb.z; ff[7] = cvb.w;
    int lab[8];
    lab[0] = cla.x; lab[1] = cla.y; lab[2] = cla.z; lab[3] = cla.w;
    lab[4] = clb.x; lab[5] = clb.y; lab[6] = clb.z; lab[7] = clb.w;
    union BF { uint32_t w[4]; bf16x8 v; } Ahi, Alo, B0, B1;
#pragma unroll
    for (int q = 0; q < 4; ++q) {
      const uint32_t u0 = __float_as_uint(ff[2 * q]);
      const uint32_t u1 = __float_as_uint(ff[2 * q + 1]);
      Ahi.w[q] = (u0 >> 16) | (u1 & 0xFFFF0000u);
      const float r0 = ff[2 * q] - __uint_as_float(u0 & 0xFFFF0000u);
      const float r1 = ff[2 * q + 1] - __uint_as_float(u1 & 0xFFFF0000u);
      Alo.w[q] = (__float_as_uint(r0) >> 16) | (__float_as_uint(r1) & 0xFFFF0000u);
      B0.w[q] = ((lab[2 * q] == cl) ? 0x3F80u : 0u) |
                ((lab[2 * q + 1] == cl) ? 0x3F800000u : 0u);
      B1.w[q] = ((lab[2 * q] == cl + 16) ? 0x3F80u : 0u) |
                ((lab[2 * q + 1] == cl + 16) ? 0x3F800000u : 0u);
    }
    acc0 = __builtin_amdgcn_mfma_f32_16x16x32_bf16(Ahi.v, B0.v, acc0, 0, 0, 0);
    acc0 = __builtin_amdgcn_mfma_f32_16x16x32_bf16(Alo.v, B0.v, acc0, 0, 0, 0);
    acc1 = __builtin_amdgcn_mfma_f32_16x16x32_bf16(Ahi.v, B1.v, acc1, 0, 0, 0);
    acc1 = __builtin_amdgcn_mfma_f32_16x16x32_bf16(Alo.v, B1.v, acc1, 0, 0, 0);
    cnt0 = __builtin_amdgcn_mfma_f32_16x16x32_bf16(ones, B0.v, cnt0, 0, 0, 0);
    cnt1 = __builtin_amdgcn_mfma_f32_16x16x32_bf16(ones, B1.v, cnt1, 0, 0, 0);
  }

#pragma unroll
  for (int r = 0; r < 4; ++r) {
    s_red[wv][0][r][l] = acc0[r];
    s_red[wv][1][r][l] = acc1[r];
  }
  if (g == 0) {
    s_cnt[wv][0][cl] = cnt0[0];
    s_cnt[wv][1][cl] = cnt1[0];
  }
  __syncthreads();

  if (partmode) {
    float* pbase = ws + WS_PART +
                   (size_t)(n * P1_BLOCKS + blockIdx.x) * PART_STRIDE;
#pragma unroll
    for (int i = tid; i < 512; i += 256) {
      const int h = i >> 8, r = (i >> 6) & 3, ll = i & 63;
      const float v = s_red[0][h][r][ll] + s_red[1][h][r][ll] +
                      s_red[2][h][r][ll] + s_red[3][h][r][ll];
      const int c = (ll & 15) + 16 * h;
      const int e = (ll >> 4) * 4 + r;
      pbase[c * E_DIM + e] = v;
    }
    if (tid < C_CL) {
      const int h = tid >> 4, c16 = tid & 15;
      pbase[512 + tid] = s_cnt[0][h][c16] + s_cnt[1][h][c16] +
                         s_cnt[2][h][c16] + s_cnt[3][h][c16];
    }
  } else {
    float* gsum = ws + WS_SUMS + n * C_CL * E_DIM;
#pragma unroll
    for (int i = tid; i < 512; i += 256) {
      const int h = i >> 8, r = (i >> 6) & 3, ll = i & 63;
      const float v = s_red[0][h][r][ll] + s_red[1][h][r][ll] +
                      s_red[2][h][r][ll] + s_red[3][h][r][ll];
      const int c = (ll & 15) + 16 * h;
      const int e = (ll >> 4) * 4 + r;
      gatomic_add(&gsum[c * E_DIM + e], v);
    }
    if (tid < C_CL) {
      const int h = tid >> 4, c16 = tid & 15;
      const float v = s_cnt[0][h][c16] + s_cnt[1][h][c16] + s_cnt[2][h][c16] +
                      s_cnt[3][h][c16];
      gatomic_add(ws + WS_CNT + n * C_CL + tid, v);
    }
  }
}

__global__ __launch_bounds__(256) void reduce1(float* __restrict__ ws) {
  __shared__ float s[8][32];
  const int tid = threadIdx.x;
  const int bs = tid >> 5, il = tid & 31;
  const int n = blockIdx.y;
  const int i = blockIdx.x * 32 + il;
  const float* part = ws + WS_PART + (size_t)n * P1_BLOCKS * PART_STRIDE;
  float acc = 0.f;
#pragma unroll 8
  for (int b = bs; b < P1_BLOCKS; b += 8) acc += part[b * PART_STRIDE + i];
  s[bs][il] = acc;
  __syncthreads();
  if (tid < 32) {
    const int ii = blockIdx.x * 32 + tid;
    float t = s[0][tid] + s[1][tid] + s[2][tid] + s[3][tid] + s[4][tid] +
              s[5][tid] + s[6][tid] + s[7][tid];
    if (ii < 512)
      ws[WS_SUMS + n * 512 + ii] = t;
    else
      ws[WS_CNT + n * C_CL + (ii - 512)] = t;
  }
}

__global__ __launch_bounds__(256) void pass2(const float* __restrict__ input,
                                             const int* __restrict__ target,
                                             float* __restrict__ ws,
                                             int hmode) {
  __shared__ float s_meanT[E_DIM][C_CL];
  __shared__ float s_icnt[C_CL];
  __shared__ float s_part[4];
  const int tid = threadIdx.x;
  const int n = blockIdx.y;
  const float* gsum = ws + WS_SUMS + n * C_CL * E_DIM;
  const float* gcnt = ws + WS_CNT + n * C_CL;
  for (int i = tid; i < C_CL * E_DIM; i += 256) {
    const int c = i >> 4, e = i & 15;
    s_meanT[e][c] = gsum[i] / gcnt[c];
  }
  if (tid < C_CL) s_icnt[tid] = 1.0f / gcnt[tid];
  __syncthreads();

  const int pA = blockIdx.x * PX2 + tid * 4;
  const int pB = pA + 1024;
  const float* inp_n = input + (size_t)n * E_DIM * P_PIX;
  const int* tgt_n = target + (size_t)n * P_PIX;
  const int4 labA = *reinterpret_cast<const int4*>(tgt_n + pA);
  const int4 labB = *reinterpret_cast<const int4*>(tgt_n + pB);
  float aA0 = 0.f, aA1 = 0.f, aA2 = 0.f, aA3 = 0.f;
  float aB0 = 0.f, aB1 = 0.f, aB2 = 0.f, aB3 = 0.f;
#pragma unroll
  for (int e = 0; e < E_DIM; ++e) {
    const float* row = inp_n + (size_t)e * P_PIX;
    const float4 vA = *reinterpret_cast<const float4*>(row + pA);
    const float4 vB = *reinterpret_cast<const float4*>(row + pB);
    float d;
    d = vA.x - s_meanT[e][labA.x]; aA0 += d * d;
    d = vA.y - s_meanT[e][labA.y]; aA1 += d * d;
    d = vA.z - s_meanT[e][labA.z]; aA2 += d * d;
    d = vA.w - s_meanT[e][labA.w]; aA3 += d * d;
    d = vB.x - s_meanT[e][labB.x]; aB0 += d * d;
    d = vB.y - s_meanT[e][labB.y]; aB1 += d * d;
    d = vB.z - s_meanT[e][labB.z]; aB2 += d * d;
    d = vB.w - s_meanT[e][labB.w]; aB3 += d * d;
  }
  float dd, h, acc = 0.f;
  dd = sqrtf(fmaxf(aA0, EPS_F)); h = fmaxf(dd - DELTA_VAR, 0.f);
  acc += h * h * s_icnt[labA.x];
  dd = sqrtf(fmaxf(aA1, EPS_F)); h = fmaxf(dd - DELTA_VAR, 0.f);
  acc += h * h * s_icnt[labA.y];
  dd = sqrtf(fmaxf(aA2, EPS_F)); h = fmaxf(dd - DELTA_VAR, 0.f);
  acc += h * h * s_icnt[labA.z];
  dd = sqrtf(fmaxf(aA3, EPS_F)); h = fmaxf(dd - DELTA_VAR, 0.f);
  acc += h * h * s_icnt[labA.w];
  dd = sqrtf(fmaxf(aB0, EPS_F)); h = fmaxf(dd - DELTA_VAR, 0.f);
  acc += h * h * s_icnt[labB.x];
  dd = sqrtf(fmaxf(aB1, EPS_F)); h = fmaxf(dd - DELTA_VAR, 0.f);
  acc += h * h * s_icnt[labB.y];
  dd = sqrtf(fmaxf(aB2, EPS_F)); h = fmaxf(dd - DELTA_VAR, 0.f);
  acc += h * h * s_icnt[labB.z];
  dd = sqrtf(fmaxf(aB3, EPS_F)); h = fmaxf(dd - DELTA_VAR, 0.f);
  acc += h * h * s_icnt[labB.w];
#pragma unroll
  for (int off = 32; off > 0; off >>= 1) acc += __shfl_down(acc, off);
  if ((tid & 63) == 0) s_part[tid >> 6] = acc;
  __syncthreads();
  if (tid == 0) {
    const float total = s_part[0] + s_part[1] + s_part[2] + s_part[3];
    if (hmode)
      ws[WS_HP + n * BLOCKS2_X + blockIdx.x] = total;
    else
      gatomic_add(ws + WS_HINGE + n, total);
  }
}

__global__ __launch_bounds__(256) void finalize(const float* __restrict__ ws,
                                                float* __restrict__ out,
                                                int hmode) {
  __shared__ float s_mean[N_IMG * C_CL * E_DIM];
  __shared__ float red[256];
  const int tid = threadIdx.x;
  for (int i = tid; i < N_IMG * C_CL * E_DIM; i += 256) {
    s_mean[i] = ws[WS_SUMS + i] / ws[WS_CNT + (i >> 4)];
  }
  __syncthreads();
  float acc = 0.f;
  if (hmode) {
    for (int i = tid; i < N_IMG * BLOCKS2_X; i += 256)
      acc += ws[WS_HP + i] * (1.0f / C_CL);
  } else {
    if (tid < N_IMG) acc += ws[WS_HINGE + tid] * (1.0f / C_CL);
  }
  for (int i = tid; i < N_IMG * C_CL; i += 256) {
    float nrm2 = 0.f;
    const float* m = s_mean + i * E_DIM;
#pragma unroll
    for (int e = 0; e < E_DIM; ++e) nrm2 += m[e] * m[e];
    acc += GAMMA_W * sqrtf(fmaxf(nrm2, EPS_F)) * (1.0f / C_CL);
  }
  for (int t = tid; t < N_IMG * C_CL * C_CL; t += 256) {
    const int n = t / (C_CL * C_CL);
    const int r = t - n * C_CL * C_CL;
    const int a = r >> 5, b = r & 31;
    if (a != b) {
      const float* ma = s_mean + (n * C_CL + a) * E_DIM;
      const float* mb = s_mean + (n * C_CL + b) * E_DIM;
      float d2 = 0.f;
#pragma unroll
      for (int e = 0; e < E_DIM; ++e) {
        const float df = ma[e] - mb[e];
        d2 += df * df;
      }
      const float dist = sqrtf(fmaxf(d2, EPS_F));
      const float hd = fmaxf(2.f * DELTA_DIST - dist, 0.f);
      acc += hd * hd * (1.0f / (C_CL * (C_CL - 1)));
    }
  }
  red[tid] = acc;
  __syncthreads();
  for (int s = 128; s > 0; s >>= 1) {
    if (tid < s) red[tid] += red[tid + s];
    __syncthreads();
  }
  if (tid == 0) out[0] = red[0] * (1.0f / N_IMG);
}

extern "C" void kernel_launch(void* const* d_in, const int* in_sizes, int n_in,
                              void* d_out, int out_size, void* d_ws,
                              size_t ws_size, hipStream_t stream) {
  const float* input = (const float*)d_in[0];
  const int* target = (const int*)d_in[1];
  float* ws = (float*)d_ws;
  float* out = (float*)d_out;

  // Fused cooperative path
  if (ws_size >= (size_t)(WS_PART + NPART_F) * 4) {
    void* args[] = {(void*)&input, (void*)&target, (void*)&ws, (void*)&out};
    hipError_t err = hipLaunchCooperativeKernel(
        (void*)fused, dim3(N_IMG * FB_PER_IMG), dim3(256), args, 0, stream);
    if (err == hipSuccess) return;
  }

  // Legacy fallback (HW-verified rounds 4/7/10/11)
  const bool big_ws = ws_size >= (size_t)(WS_PART + NPART_L) * 4;
  const bool mid_ws = ws_size >= (size_t)WS_PART * 4;
  const int partmode = big_ws ? 1 : 0;
  const int hmode = mid_ws ? 1 : 0;
  if (!big_ws || !mid_ws) {
    hipMemsetAsync(ws, 0, 2180 * sizeof(float), stream);
  }
  dim3 grid1(P1_BLOCKS, N_IMG);
  pass1<<<grid1, 256, 0, stream>>>(input, target, ws, partmode);
  if (big_ws) {
    dim3 gridr(17, N_IMG);
    reduce1<<<gridr, 256, 0, stream>>>(ws);
  }
  dim3 grid2(BLOCKS2_X, N_IMG);
  pass2<<<grid2, 256, 0, stream>>>(input, target, ws, hmode);
  finalize<<<1, 256, 0, stream>>>(ws, out, hmode);
}

// Round 13
// 274.478 us; speedup vs baseline: 2.9476x; 2.9476x over previous
//
#include <hip/hip_runtime.h>
#include <stdint.h>

// Problem constants (fixed by setup_inputs)
#define N_IMG 4
#define E_DIM 16
#define H_DIM 768
#define W_DIM 768
#define P_PIX (H_DIM * W_DIM)   // 589824 pixels per image
#define C_CL 32

#define DELTA_VAR 0.5f
#define DELTA_DIST 2.0f
#define GAMMA_W 0.001f
#define EPS_F 1e-12f

// Workspace layout (floats):
//   [0,    2048): sums   [N][C][E]        (c*16+e)
//   [2048, 2176): counts [N][C]
//   [2176, 4480): pass2 per-block hinge partials [N][288] (mid/big path)
//                 (fallback: scalar hinge per image at [2176, 2180))
//   [4480, ...) : pass1 per-block partials [N][288][544]  (big path)
#define WS_SUMS 0
#define WS_CNT 2048
#define WS_HINGE 2176
#define WS_HP 2176
#define WS_PART 4480
#define PART_STRIDE 544   // 512 sums + 32 counts per block
#define P1_BLOCKS 288     // per image; 4 waves x 512 px = 2048 px/block
#define NPART_L (N_IMG * P1_BLOCKS * PART_STRIDE)

// Pass 1 staging: 2 rounds of 256 px per wave; LDS plane stride 260 floats
// (1040 B, 16B-aligned; ds_read start bank 4*cl+8*g -> <=8-way, ~1us total).
#define P1_ROUNDS 2
#define STG 260

// Pass 2 geometry (r11 linear-stream version, unchanged)
#define PX2 2048
#define BLOCKS2_X (P_PIX / PX2) // 288

using bf16x8 = __attribute__((ext_vector_type(8))) short;
using f32x4 = __attribute__((ext_vector_type(4))) float;

__device__ __forceinline__ void gatomic_add(float* p, float v) {
#if defined(__HIP_DEVICE_COMPILE__)
  unsafeAtomicAdd(p, v);
#else
  atomicAdd(p, v);
#endif
}

// Pass 1: segment-sum as MFMA (math identical to HW-verified r4/r7/r10/r11).
// KEY CHANGE (r12 fused-probe diagnosis): plane stride 2,359,296 B == 0 mod
// 32KiB L1 (and 0 mod 256KiB L2 set-group) -> the old g-interleaved staging
// load put 32 lines into 2-3 L1 sets per instruction: thrash + MSHR storm,
// ~2 TB/s effective, 92-97% SIMD stall at 8% VALUBusy. Now each wave stages
// plane-major: per 256-px round, 16 loads of (64 lanes x contiguous 16B from
// ONE plane) -> 16 lines across 16 consecutive sets, each line fetched once;
// redistribute via wave-private LDS (in-order DS pipe, no barrier needed).
__global__ __launch_bounds__(256) void pass1(const float* __restrict__ input,
                                             const int* __restrict__ target,
                                             float* __restrict__ ws,
                                             int partmode) {
  __shared__ float s_stage[4][16 * STG];  // 66560 B
  __shared__ int s_ltab[4][STG];          // 4160 B
  __shared__ float s_red[4][2][4][64];    // 8192 B
  __shared__ float s_cnt[4][2][16];       // 512 B
  const int tid = threadIdx.x;
  const int wv = tid >> 6, l = tid & 63;
  const int g = l >> 4, cl = l & 15;
  const int n = blockIdx.y;

  const int wid = blockIdx.x * 4 + wv;          // [0,1152) per image
  const int wave_base = wid * 512;
  const float* inp_n = input + (size_t)n * E_DIM * P_PIX;
  const int* tgt = target + (size_t)n * P_PIX;

  f32x4 acc0 = {0.f, 0.f, 0.f, 0.f}, acc1 = {0.f, 0.f, 0.f, 0.f};
  f32x4 cnt0 = {0.f, 0.f, 0.f, 0.f}, cnt1 = {0.f, 0.f, 0.f, 0.f};
  const short ONE = (short)0x3F80;
  const bf16x8 ones = {ONE, ONE, ONE, ONE, ONE, ONE, ONE, ONE};

  for (int r = 0; r < P1_ROUNDS; ++r) {
    const int rbase = wave_base + r * 256;
    // Plane-major staging: 16 independent contiguous 1KB wave-loads.
    float4 stg[16];
#pragma unroll
    for (int p = 0; p < 16; ++p)
      stg[p] = *reinterpret_cast<const float4*>(inp_n + (size_t)p * P_PIX +
                                                rbase + l * 4);
    const int4 stl = *reinterpret_cast<const int4*>(tgt + rbase + l * 4);
#pragma unroll
    for (int p = 0; p < 16; ++p)
      *reinterpret_cast<float4*>(&s_stage[wv][p * STG + l * 4]) = stg[p];
    *reinterpret_cast<int4*>(&s_ltab[wv][l * 4]) = stl;
    // wave-private LDS: ds_write -> ds_read ordered by in-order DS pipe.

    for (int t = 0; t < 8; ++t) {
      const int off = t * 32 + g * 8;
      const float4 cva =
          *reinterpret_cast<const float4*>(&s_stage[wv][cl * STG + off]);
      const float4 cvb =
          *reinterpret_cast<const float4*>(&s_stage[wv][cl * STG + off + 4]);
      const int4 cla = *reinterpret_cast<const int4*>(&s_ltab[wv][off]);
      const int4 clb = *reinterpret_cast<const int4*>(&s_ltab[wv][off + 4]);

      float ff[8];
      ff[0] = cva.x; ff[1] = cva.y; ff[2] = cva.z; ff[3] = cva.w;
      ff[4] = cvb.x; ff[5] = cvb.y; ff[6] = cvb.z; ff[7] = cvb.w;
      int lab[8];
      lab[0] = cla.x; lab[1] = cla.y; lab[2] = cla.z; lab[3] = cla.w;
      lab[4] = clb.x; lab[5] = clb.y; lab[6] = clb.z; lab[7] = clb.w;

      // bf16 hi+lo split (exact residual): fp32-grade accumulation.
      union BF { uint32_t w[4]; bf16x8 v; } Ahi, Alo, B0, B1;
#pragma unroll
      for (int q = 0; q < 4; ++q) {
        const uint32_t u0 = __float_as_uint(ff[2 * q]);
        const uint32_t u1 = __float_as_uint(ff[2 * q + 1]);
        Ahi.w[q] = (u0 >> 16) | (u1 & 0xFFFF0000u);
        const float r0 = ff[2 * q] - __uint_as_float(u0 & 0xFFFF0000u);
        const float r1 = ff[2 * q + 1] - __uint_as_float(u1 & 0xFFFF0000u);
        Alo.w[q] =
            (__float_as_uint(r0) >> 16) | (__float_as_uint(r1) & 0xFFFF0000u);
        B0.w[q] = ((lab[2 * q] == cl) ? 0x3F80u : 0u) |
                  ((lab[2 * q + 1] == cl) ? 0x3F800000u : 0u);
        B1.w[q] = ((lab[2 * q] == cl + 16) ? 0x3F80u : 0u) |
                  ((lab[2 * q + 1] == cl + 16) ? 0x3F800000u : 0u);
      }
      acc0 = __builtin_amdgcn_mfma_f32_16x16x32_bf16(Ahi.v, B0.v, acc0, 0, 0, 0);
      acc0 = __builtin_amdgcn_mfma_f32_16x16x32_bf16(Alo.v, B0.v, acc0, 0, 0, 0);
      acc1 = __builtin_amdgcn_mfma_f32_16x16x32_bf16(Ahi.v, B1.v, acc1, 0, 0, 0);
      acc1 = __builtin_amdgcn_mfma_f32_16x16x32_bf16(Alo.v, B1.v, acc1, 0, 0, 0);
      cnt0 = __builtin_amdgcn_mfma_f32_16x16x32_bf16(ones, B0.v, cnt0, 0, 0, 0);
      cnt1 = __builtin_amdgcn_mfma_f32_16x16x32_bf16(ones, B1.v, cnt1, 0, 0, 0);
    }
  }

  // Block reduction (8 KB LDS) -> store-flush (no contended atomics, r4 fix).
#pragma unroll
  for (int r = 0; r < 4; ++r) {
    s_red[wv][0][r][l] = acc0[r];
    s_red[wv][1][r][l] = acc1[r];
  }
  if (g == 0) {
    s_cnt[wv][0][cl] = cnt0[0];
    s_cnt[wv][1][cl] = cnt1[0];
  }
  __syncthreads();

  if (partmode) {
    float* pbase = ws + WS_PART +
                   (size_t)(n * P1_BLOCKS + blockIdx.x) * PART_STRIDE;
#pragma unroll
    for (int i = tid; i < 512; i += 256) {
      const int h = i >> 8, r = (i >> 6) & 3, ll = i & 63;
      const float v = s_red[0][h][r][ll] + s_red[1][h][r][ll] +
                      s_red[2][h][r][ll] + s_red[3][h][r][ll];
      const int c = (ll & 15) + 16 * h;
      const int e = (ll >> 4) * 4 + r;
      pbase[c * E_DIM + e] = v;
    }
    if (tid < C_CL) {
      const int h = tid >> 4, c16 = tid & 15;
      pbase[512 + tid] = s_cnt[0][h][c16] + s_cnt[1][h][c16] +
                         s_cnt[2][h][c16] + s_cnt[3][h][c16];
    }
  } else {
    float* gsum = ws + WS_SUMS + n * C_CL * E_DIM;
#pragma unroll
    for (int i = tid; i < 512; i += 256) {
      const int h = i >> 8, r = (i >> 6) & 3, ll = i & 63;
      const float v = s_red[0][h][r][ll] + s_red[1][h][r][ll] +
                      s_red[2][h][r][ll] + s_red[3][h][r][ll];
      const int c = (ll & 15) + 16 * h;
      const int e = (ll >> 4) * 4 + r;
      gatomic_add(&gsum[c * E_DIM + e], v);
    }
    if (tid < C_CL) {
      const int h = tid >> 4, c16 = tid & 15;
      const float v = s_cnt[0][h][c16] + s_cnt[1][h][c16] + s_cnt[2][h][c16] +
                      s_cnt[3][h][c16];
      gatomic_add(ws + WS_CNT + n * C_CL + tid, v);
    }
  }
}

// Reduce pass1 partials: sums[n][i] = sum_b part[n][b][i]. grid (17, N_IMG).
__global__ __launch_bounds__(256) void reduce1(float* __restrict__ ws) {
  __shared__ float s[8][32];
  const int tid = threadIdx.x;
  const int bs = tid >> 5, il = tid & 31;
  const int n = blockIdx.y;
  const int i = blockIdx.x * 32 + il;  // [0,544)
  const float* part = ws + WS_PART + (size_t)n * P1_BLOCKS * PART_STRIDE;
  float acc = 0.f;
#pragma unroll 8
  for (int b = bs; b < P1_BLOCKS; b += 8) acc += part[b * PART_STRIDE + i];
  s[bs][il] = acc;
  __syncthreads();
  if (tid < 32) {
    const int ii = blockIdx.x * 32 + tid;
    float t = s[0][tid] + s[1][tid] + s[2][tid] + s[3][tid] + s[4][tid] +
              s[5][tid] + s[6][tid] + s[7][tid];
    if (ii < 512)
      ws[WS_SUMS + n * 512 + ii] = t;
    else
      ws[WS_CNT + n * C_CL + (ii - 512)] = t;
  }
}

// Pass 2: r11 linear-stream hinge (loads already lane-contiguous -> clean
// L1 sets; unchanged for attribution).
__global__ __launch_bounds__(256) void pass2(const float* __restrict__ input,
                                             const int* __restrict__ target,
                                             float* __restrict__ ws,
                                             int hmode) {
  __shared__ float s_meanT[E_DIM][C_CL];
  __shared__ float s_icnt[C_CL];
  __shared__ float s_part[4];
  const int tid = threadIdx.x;
  const int n = blockIdx.y;
  const float* gsum = ws + WS_SUMS + n * C_CL * E_DIM;
  const float* gcnt = ws + WS_CNT + n * C_CL;
  for (int i = tid; i < C_CL * E_DIM; i += 256) {
    const int c = i >> 4, e = i & 15;
    s_meanT[e][c] = gsum[i] / gcnt[c];
  }
  if (tid < C_CL) s_icnt[tid] = 1.0f / gcnt[tid];
  __syncthreads();

  const int pA = blockIdx.x * PX2 + tid * 4;
  const int pB = pA + 1024;
  const float* inp_n = input + (size_t)n * E_DIM * P_PIX;
  const int* tgt_n = target + (size_t)n * P_PIX;
  const int4 labA = *reinterpret_cast<const int4*>(tgt_n + pA);
  const int4 labB = *reinterpret_cast<const int4*>(tgt_n + pB);
  float aA0 = 0.f, aA1 = 0.f, aA2 = 0.f, aA3 = 0.f;
  float aB0 = 0.f, aB1 = 0.f, aB2 = 0.f, aB3 = 0.f;
#pragma unroll
  for (int e = 0; e < E_DIM; ++e) {
    const float* row = inp_n + (size_t)e * P_PIX;
    const float4 vA = *reinterpret_cast<const float4*>(row + pA);
    const float4 vB = *reinterpret_cast<const float4*>(row + pB);
    float d;
    d = vA.x - s_meanT[e][labA.x]; aA0 += d * d;
    d = vA.y - s_meanT[e][labA.y]; aA1 += d * d;
    d = vA.z - s_meanT[e][labA.z]; aA2 += d * d;
    d = vA.w - s_meanT[e][labA.w]; aA3 += d * d;
    d = vB.x - s_meanT[e][labB.x]; aB0 += d * d;
    d = vB.y - s_meanT[e][labB.y]; aB1 += d * d;
    d = vB.z - s_meanT[e][labB.z]; aB2 += d * d;
    d = vB.w - s_meanT[e][labB.w]; aB3 += d * d;
  }
  float dd, h, acc = 0.f;
  dd = sqrtf(fmaxf(aA0, EPS_F)); h = fmaxf(dd - DELTA_VAR, 0.f);
  acc += h * h * s_icnt[labA.x];
  dd = sqrtf(fmaxf(aA1, EPS_F)); h = fmaxf(dd - DELTA_VAR, 0.f);
  acc += h * h * s_icnt[labA.y];
  dd = sqrtf(fmaxf(aA2, EPS_F)); h = fmaxf(dd - DELTA_VAR, 0.f);
  acc += h * h * s_icnt[labA.z];
  dd = sqrtf(fmaxf(aA3, EPS_F)); h = fmaxf(dd - DELTA_VAR, 0.f);
  acc += h * h * s_icnt[labA.w];
  dd = sqrtf(fmaxf(aB0, EPS_F)); h = fmaxf(dd - DELTA_VAR, 0.f);
  acc += h * h * s_icnt[labB.x];
  dd = sqrtf(fmaxf(aB1, EPS_F)); h = fmaxf(dd - DELTA_VAR, 0.f);
  acc += h * h * s_icnt[labB.y];
  dd = sqrtf(fmaxf(aB2, EPS_F)); h = fmaxf(dd - DELTA_VAR, 0.f);
  acc += h * h * s_icnt[labB.z];
  dd = sqrtf(fmaxf(aB3, EPS_F)); h = fmaxf(dd - DELTA_VAR, 0.f);
  acc += h * h * s_icnt[labB.w];
#pragma unroll
  for (int off = 32; off > 0; off >>= 1) acc += __shfl_down(acc, off);
  if ((tid & 63) == 0) s_part[tid >> 6] = acc;
  __syncthreads();
  if (tid == 0) {
    const float total = s_part[0] + s_part[1] + s_part[2] + s_part[3];
    if (hmode)
      ws[WS_HP + n * BLOCKS2_X + blockIdx.x] = total;
    else
      gatomic_add(ws + WS_HINGE + n, total);
  }
}

// Finalize: variance + distance + regularizer -> scalar.
__global__ __launch_bounds__(256) void finalize(const float* __restrict__ ws,
                                                float* __restrict__ out,
                                                int hmode) {
  __shared__ float s_mean[N_IMG * C_CL * E_DIM];
  __shared__ float red[256];
  const int tid = threadIdx.x;
  for (int i = tid; i < N_IMG * C_CL * E_DIM; i += 256) {
    s_mean[i] = ws[WS_SUMS + i] / ws[WS_CNT + (i >> 4)];
  }
  __syncthreads();
  float acc = 0.f;
  if (hmode) {
    for (int i = tid; i < N_IMG * BLOCKS2_X; i += 256)
      acc += ws[WS_HP + i] * (1.0f / C_CL);
  } else {
    if (tid < N_IMG) acc += ws[WS_HINGE + tid] * (1.0f / C_CL);
  }
  for (int i = tid; i < N_IMG * C_CL; i += 256) {
    float nrm2 = 0.f;
    const float* m = s_mean + i * E_DIM;
#pragma unroll
    for (int e = 0; e < E_DIM; ++e) nrm2 += m[e] * m[e];
    acc += GAMMA_W * sqrtf(fmaxf(nrm2, EPS_F)) * (1.0f / C_CL);
  }
  for (int t = tid; t < N_IMG * C_CL * C_CL; t += 256) {
    const int n = t / (C_CL * C_CL);
    const int r = t - n * C_CL * C_CL;
    const int a = r >> 5, b = r & 31;
    if (a != b) {
      const float* ma = s_mean + (n * C_CL + a) * E_DIM;
      const float* mb = s_mean + (n * C_CL + b) * E_DIM;
      float d2 = 0.f;
#pragma unroll
      for (int e = 0; e < E_DIM; ++e) {
        const float df = ma[e] - mb[e];
        d2 += df * df;
      }
      const float dist = sqrtf(fmaxf(d2, EPS_F));
      const float hd = fmaxf(2.f * DELTA_DIST - dist, 0.f);
      acc += hd * hd * (1.0f / (C_CL * (C_CL - 1)));
    }
  }
  red[tid] = acc;
  __syncthreads();
  for (int s = 128; s > 0; s >>= 1) {
    if (tid < s) red[tid] += red[tid + s];
    __syncthreads();
  }
  if (tid == 0) out[0] = red[0] * (1.0f / N_IMG);
}

extern "C" void kernel_launch(void* const* d_in, const int* in_sizes, int n_in,
                              void* d_out, int out_size, void* d_ws,
                              size_t ws_size, hipStream_t stream) {
  const float* input = (const float*)d_in[0];
  const int* target = (const int*)d_in[1];
  float* ws = (float*)d_ws;
  float* out = (float*)d_out;

  const bool big_ws = ws_size >= (size_t)(WS_PART + NPART_L) * 4;
  const bool mid_ws = ws_size >= (size_t)WS_PART * 4;
  const int partmode = big_ws ? 1 : 0;
  const int hmode = mid_ws ? 1 : 0;
  if (!big_ws || !mid_ws) {
    hipMemsetAsync(ws, 0, 2180 * sizeof(float), stream);
  }
  dim3 grid1(P1_BLOCKS, N_IMG);
  pass1<<<grid1, 256, 0, stream>>>(input, target, ws, partmode);
  if (big_ws) {
    dim3 gridr(17, N_IMG);
    reduce1<<<gridr, 256, 0, stream>>>(ws);
  }
  dim3 grid2(BLOCKS2_X, N_IMG);
  pass2<<<grid2, 256, 0, stream>>>(input, target, ws, hmode);
  finalize<<<1, 256, 0, stream>>>(ws, out, hmode);
}

// Round 14
// 273.725 us; speedup vs baseline: 2.9557x; 1.0028x over previous
//
#include <hip/hip_runtime.h>
#include <stdint.h>

// Problem constants (fixed by setup_inputs)
#define N_IMG 4
#define E_DIM 16
#define H_DIM 768
#define W_DIM 768
#define P_PIX (H_DIM * W_DIM)   // 589824 pixels per image
#define C_CL 32

#define DELTA_VAR 0.5f
#define DELTA_DIST 2.0f
#define GAMMA_W 0.001f
#define EPS_F 1e-12f

// Workspace layout (floats):
//   [0,    2048): sums   [N][C][E]        (c*16+e)
//   [2048, 2176): counts [N][C]
//   [2176, 4480): pass2 per-block hinge partials [N][288] (mid/big path)
//                 (fallback: scalar hinge per image at [2176, 2180))
//   [4480, ...) : pass1 per-block partials [N][576][544]  (big path)
//                 (probe scribbles here BEFORE pass1 overwrites every slot)
#define WS_SUMS 0
#define WS_CNT 2048
#define WS_HINGE 2176
#define WS_HP 2176
#define WS_PART 4480
#define PART_STRIDE 544
#define P1_BLOCKS 576
#define P1_TILES 8
#define NPART_L (N_IMG * P1_BLOCKS * PART_STRIDE)

#define PX2 2048
#define BLOCKS2_X (P_PIX / PX2) // 288

#define PROBE_BLOCKS 2048

using bf16x8 = __attribute__((ext_vector_type(8))) short;
using f32x4 = __attribute__((ext_vector_type(4))) float;

__device__ __forceinline__ void gatomic_add(float* p, float v) {
#if defined(__HIP_DEVICE_COMPILE__)
  unsafeAtomicAdd(p, v);
#else
  atomicAdd(p, v);
#endif
}

// ---- READ-BW PROBE -------------------------------------------------------
// r13 evidence: every input-reading kernel lands at ~1.9 TB/s logical read
// (86 us) across 5 structures, occupancies 9-43%, and is insensitive to
// memory source (L3-warm replay same dur). Theory: ~2 TB/s read ceiling for
// load-issuing kernels on this box. This probe is the canonical 6.3 TB/s
// pattern (flat contiguous grid-stride float4, 2048 blocks): its counters
// next round directly confirm/refute. Output: dead partial per block into
// the pass1-partials region (pass1 fully overwrites before reduce1 reads).
__global__ __launch_bounds__(256) void probe(const float* __restrict__ in,
                                             float* __restrict__ ws) {
  __shared__ float sp[4];
  const size_t total = (size_t)N_IMG * E_DIM * P_PIX;  // floats
  float acc = 0.f;
  for (size_t i = ((size_t)blockIdx.x * 256 + threadIdx.x) * 4; i < total;
       i += (size_t)PROBE_BLOCKS * 256 * 4) {
    const float4 v = *reinterpret_cast<const float4*>(in + i);
    acc += v.x + v.y + v.z + v.w;
  }
#pragma unroll
  for (int off = 32; off > 0; off >>= 1) acc += __shfl_down(acc, off);
  if ((threadIdx.x & 63) == 0) sp[threadIdx.x >> 6] = acc;
  __syncthreads();
  if (threadIdx.x == 0)
    ws[WS_PART + blockIdx.x] = sp[0] + sp[1] + sp[2] + sp[3];
}

// Pass 1: segment-sum as MFMA (HW-verified r4/r7/r10/r11 configuration,
// byte-identical to r11: g-interleaved loads, store-flush, 576 blocks/img).
__global__ __launch_bounds__(256) void pass1(const float* __restrict__ input,
                                             const int* __restrict__ target,
                                             float* __restrict__ ws,
                                             int partmode) {
  __shared__ float s_red[4][2][4][64];
  __shared__ float s_cnt[4][2][16];
  const int tid = threadIdx.x;
  const int wv = tid >> 6, l = tid & 63;
  const int g = l >> 4, cl = l & 15;
  const int n = blockIdx.y;
  const int wid = blockIdx.x * 4 + wv;
  const int base = wid * (P1_TILES * 32) + g * 8;
  const float* rowp = input + ((size_t)n * E_DIM + cl) * P_PIX;
  const int* tgt = target + (size_t)n * P_PIX;

  f32x4 acc0 = {0.f, 0.f, 0.f, 0.f}, acc1 = {0.f, 0.f, 0.f, 0.f};
  f32x4 cnt0 = {0.f, 0.f, 0.f, 0.f}, cnt1 = {0.f, 0.f, 0.f, 0.f};
  const short ONE = (short)0x3F80;
  const bf16x8 ones = {ONE, ONE, ONE, ONE, ONE, ONE, ONE, ONE};

  float4 va = *reinterpret_cast<const float4*>(rowp + base);
  float4 vb = *reinterpret_cast<const float4*>(rowp + base + 4);
  int4 la = *reinterpret_cast<const int4*>(tgt + base);
  int4 lb = *reinterpret_cast<const int4*>(tgt + base + 4);

  for (int t = 0; t < P1_TILES; ++t) {
    const float4 cva = va, cvb = vb;
    const int4 cla = la, clb = lb;
    if (t + 1 < P1_TILES) {
      const int p = base + (t + 1) * 32;
      va = *reinterpret_cast<const float4*>(rowp + p);
      vb = *reinterpret_cast<const float4*>(rowp + p + 4);
      la = *reinterpret_cast<const int4*>(tgt + p);
      lb = *reinterpret_cast<const int4*>(tgt + p + 4);
    }
    float ff[8];
    ff[0] = cva.x; ff[1] = cva.y; ff[2] = cva.z; ff[3] = cva.w;
    ff[4] = cvb.x; ff[5] = cvb.y; ff[6] = cvb.z; ff[7] = cvb.w;
    int lab[8];
    lab[0] = cla.x; lab[1] = cla.y; lab[2] = cla.z; lab[3] = cla.w;
    lab[4] = clb.x; lab[5] = clb.y; lab[6] = clb.z; lab[7] = clb.w;
    union BF { uint32_t w[4]; bf16x8 v; } Ahi, Alo, B0, B1;
#pragma unroll
    for (int q = 0; q < 4; ++q) {
      const uint32_t u0 = __float_as_uint(ff[2 * q]);
      const uint32_t u1 = __float_as_uint(ff[2 * q + 1]);
      Ahi.w[q] = (u0 >> 16) | (u1 & 0xFFFF0000u);
      const float r0 = ff[2 * q] - __uint_as_float(u0 & 0xFFFF0000u);
      const float r1 = ff[2 * q + 1] - __uint_as_float(u1 & 0xFFFF0000u);
      Alo.w[q] = (__float_as_uint(r0) >> 16) | (__float_as_uint(r1) & 0xFFFF0000u);
      B0.w[q] = ((lab[2 * q] == cl) ? 0x3F80u : 0u) |
                ((lab[2 * q + 1] == cl) ? 0x3F800000u : 0u);
      B1.w[q] = ((lab[2 * q] == cl + 16) ? 0x3F80u : 0u) |
                ((lab[2 * q + 1] == cl + 16) ? 0x3F800000u : 0u);
    }
    acc0 = __builtin_amdgcn_mfma_f32_16x16x32_bf16(Ahi.v, B0.v, acc0, 0, 0, 0);
    acc0 = __builtin_amdgcn_mfma_f32_16x16x32_bf16(Alo.v, B0.v, acc0, 0, 0, 0);
    acc1 = __builtin_amdgcn_mfma_f32_16x16x32_bf16(Ahi.v, B1.v, acc1, 0, 0, 0);
    acc1 = __builtin_amdgcn_mfma_f32_16x16x32_bf16(Alo.v, B1.v, acc1, 0, 0, 0);
    cnt0 = __builtin_amdgcn_mfma_f32_16x16x32_bf16(ones, B0.v, cnt0, 0, 0, 0);
    cnt1 = __builtin_amdgcn_mfma_f32_16x16x32_bf16(ones, B1.v, cnt1, 0, 0, 0);
  }

#pragma unroll
  for (int r = 0; r < 4; ++r) {
    s_red[wv][0][r][l] = acc0[r];
    s_red[wv][1][r][l] = acc1[r];
  }
  if (g == 0) {
    s_cnt[wv][0][cl] = cnt0[0];
    s_cnt[wv][1][cl] = cnt1[0];
  }
  __syncthreads();

  if (partmode) {
    float* pbase = ws + WS_PART +
                   (size_t)(n * P1_BLOCKS + blockIdx.x) * PART_STRIDE;
#pragma unroll
    for (int i = tid; i < 512; i += 256) {
      const int h = i >> 8, r = (i >> 6) & 3, ll = i & 63;
      const float v = s_red[0][h][r][ll] + s_red[1][h][r][ll] +
                      s_red[2][h][r][ll] + s_red[3][h][r][ll];
      const int c = (ll & 15) + 16 * h;
      const int e = (ll >> 4) * 4 + r;
      pbase[c * E_DIM + e] = v;
    }
    if (tid < C_CL) {
      const int h = tid >> 4, c16 = tid & 15;
      pbase[512 + tid] = s_cnt[0][h][c16] + s_cnt[1][h][c16] +
                         s_cnt[2][h][c16] + s_cnt[3][h][c16];
    }
  } else {
    float* gsum = ws + WS_SUMS + n * C_CL * E_DIM;
#pragma unroll
    for (int i = tid; i < 512; i += 256) {
      const int h = i >> 8, r = (i >> 6) & 3, ll = i & 63;
      const float v = s_red[0][h][r][ll] + s_red[1][h][r][ll] +
                      s_red[2][h][r][ll] + s_red[3][h][r][ll];
      const int c = (ll & 15) + 16 * h;
      const int e = (ll >> 4) * 4 + r;
      gatomic_add(&gsum[c * E_DIM + e], v);
    }
    if (tid < C_CL) {
      const int h = tid >> 4, c16 = tid & 15;
      const float v = s_cnt[0][h][c16] + s_cnt[1][h][c16] + s_cnt[2][h][c16] +
                      s_cnt[3][h][c16];
      gatomic_add(ws + WS_CNT + n * C_CL + tid, v);
    }
  }
}

__global__ __launch_bounds__(256) void reduce1(float* __restrict__ ws) {
  __shared__ float s[8][32];
  const int tid = threadIdx.x;
  const int bs = tid >> 5, il = tid & 31;
  const int n = blockIdx.y;
  const int i = blockIdx.x * 32 + il;
  const float* part = ws + WS_PART + (size_t)n * P1_BLOCKS * PART_STRIDE;
  float acc = 0.f;
#pragma unroll 8
  for (int b = bs; b < P1_BLOCKS; b += 8) acc += part[b * PART_STRIDE + i];
  s[bs][il] = acc;
  __syncthreads();
  if (tid < 32) {
    const int ii = blockIdx.x * 32 + tid;
    float t = s[0][tid] + s[1][tid] + s[2][tid] + s[3][tid] + s[4][tid] +
              s[5][tid] + s[6][tid] + s[7][tid];
    if (ii < 512)
      ws[WS_SUMS + n * 512 + ii] = t;
    else
      ws[WS_CNT + n * C_CL + (ii - 512)] = t;
  }
}

// Pass 2: r11 linear-stream hinge (byte-identical).
__global__ __launch_bounds__(256) void pass2(const float* __restrict__ input,
                                             const int* __restrict__ target,
                                             float* __restrict__ ws,
                                             int hmode) {
  __shared__ float s_meanT[E_DIM][C_CL];
  __shared__ float s_icnt[C_CL];
  __shared__ float s_part[4];
  const int tid = threadIdx.x;
  const int n = blockIdx.y;
  const float* gsum = ws + WS_SUMS + n * C_CL * E_DIM;
  const float* gcnt = ws + WS_CNT + n * C_CL;
  for (int i = tid; i < C_CL * E_DIM; i += 256) {
    const int c = i >> 4, e = i & 15;
    s_meanT[e][c] = gsum[i] / gcnt[c];
  }
  if (tid < C_CL) s_icnt[tid] = 1.0f / gcnt[tid];
  __syncthreads();

  const int pA = blockIdx.x * PX2 + tid * 4;
  const int pB = pA + 1024;
  const float* inp_n = input + (size_t)n * E_DIM * P_PIX;
  const int* tgt_n = target + (size_t)n * P_PIX;
  const int4 labA = *reinterpret_cast<const int4*>(tgt_n + pA);
  const int4 labB = *reinterpret_cast<const int4*>(tgt_n + pB);
  float aA0 = 0.f, aA1 = 0.f, aA2 = 0.f, aA3 = 0.f;
  float aB0 = 0.f, aB1 = 0.f, aB2 = 0.f, aB3 = 0.f;
#pragma unroll
  for (int e = 0; e < E_DIM; ++e) {
    const float* row = inp_n + (size_t)e * P_PIX;
    const float4 vA = *reinterpret_cast<const float4*>(row + pA);
    const float4 vB = *reinterpret_cast<const float4*>(row + pB);
    float d;
    d = vA.x - s_meanT[e][labA.x]; aA0 += d * d;
    d = vA.y - s_meanT[e][labA.y]; aA1 += d * d;
    d = vA.z - s_meanT[e][labA.z]; aA2 += d * d;
    d = vA.w - s_meanT[e][labA.w]; aA3 += d * d;
    d = vB.x - s_meanT[e][labB.x]; aB0 += d * d;
    d = vB.y - s_meanT[e][labB.y]; aB1 += d * d;
    d = vB.z - s_meanT[e][labB.z]; aB2 += d * d;
    d = vB.w - s_meanT[e][labB.w]; aB3 += d * d;
  }
  float dd, h, acc = 0.f;
  dd = sqrtf(fmaxf(aA0, EPS_F)); h = fmaxf(dd - DELTA_VAR, 0.f);
  acc += h * h * s_icnt[labA.x];
  dd = sqrtf(fmaxf(aA1, EPS_F)); h = fmaxf(dd - DELTA_VAR, 0.f);
  acc += h * h * s_icnt[labA.y];
  dd = sqrtf(fmaxf(aA2, EPS_F)); h = fmaxf(dd - DELTA_VAR, 0.f);
  acc += h * h * s_icnt[labA.z];
  dd = sqrtf(fmaxf(aA3, EPS_F)); h = fmaxf(dd - DELTA_VAR, 0.f);
  acc += h * h * s_icnt[labA.w];
  dd = sqrtf(fmaxf(aB0, EPS_F)); h = fmaxf(dd - DELTA_VAR, 0.f);
  acc += h * h * s_icnt[labB.x];
  dd = sqrtf(fmaxf(aB1, EPS_F)); h = fmaxf(dd - DELTA_VAR, 0.f);
  acc += h * h * s_icnt[labB.y];
  dd = sqrtf(fmaxf(aB2, EPS_F)); h = fmaxf(dd - DELTA_VAR, 0.f);
  acc += h * h * s_icnt[labB.z];
  dd = sqrtf(fmaxf(aB3, EPS_F)); h = fmaxf(dd - DELTA_VAR, 0.f);
  acc += h * h * s_icnt[labB.w];
#pragma unroll
  for (int off = 32; off > 0; off >>= 1) acc += __shfl_down(acc, off);
  if ((tid & 63) == 0) s_part[tid >> 6] = acc;
  __syncthreads();
  if (tid == 0) {
    const float total = s_part[0] + s_part[1] + s_part[2] + s_part[3];
    if (hmode)
      ws[WS_HP + n * BLOCKS2_X + blockIdx.x] = total;
    else
      gatomic_add(ws + WS_HINGE + n, total);
  }
}

__global__ __launch_bounds__(256) void finalize(const float* __restrict__ ws,
                                                float* __restrict__ out,
                                                int hmode) {
  __shared__ float s_mean[N_IMG * C_CL * E_DIM];
  __shared__ float red[256];
  const int tid = threadIdx.x;
  for (int i = tid; i < N_IMG * C_CL * E_DIM; i += 256) {
    s_mean[i] = ws[WS_SUMS + i] / ws[WS_CNT + (i >> 4)];
  }
  __syncthreads();
  float acc = 0.f;
  if (hmode) {
    for (int i = tid; i < N_IMG * BLOCKS2_X; i += 256)
      acc += ws[WS_HP + i] * (1.0f / C_CL);
  } else {
    if (tid < N_IMG) acc += ws[WS_HINGE + tid] * (1.0f / C_CL);
  }
  for (int i = tid; i < N_IMG * C_CL; i += 256) {
    float nrm2 = 0.f;
    const float* m = s_mean + i * E_DIM;
#pragma unroll
    for (int e = 0; e < E_DIM; ++e) nrm2 += m[e] * m[e];
    acc += GAMMA_W * sqrtf(fmaxf(nrm2, EPS_F)) * (1.0f / C_CL);
  }
  for (int t = tid; t < N_IMG * C_CL * C_CL; t += 256) {
    const int n = t / (C_CL * C_CL);
    const int r = t - n * C_CL * C_CL;
    const int a = r >> 5, b = r & 31;
    if (a != b) {
      const float* ma = s_mean + (n * C_CL + a) * E_DIM;
      const float* mb = s_mean + (n * C_CL + b) * E_DIM;
      float d2 = 0.f;
#pragma unroll
      for (int e = 0; e < E_DIM; ++e) {
        const float df = ma[e] - mb[e];
        d2 += df * df;
      }
      const float dist = sqrtf(fmaxf(d2, EPS_F));
      const float hd = fmaxf(2.f * DELTA_DIST - dist, 0.f);
      acc += hd * hd * (1.0f / (C_CL * (C_CL - 1)));
    }
  }
  red[tid] = acc;
  __syncthreads();
  for (int s = 128; s > 0; s >>= 1) {
    if (tid < s) red[tid] += red[tid + s];
    __syncthreads();
  }
  if (tid == 0) out[0] = red[0] * (1.0f / N_IMG);
}

extern "C" void kernel_launch(void* const* d_in, const int* in_sizes, int n_in,
                              void* d_out, int out_size, void* d_ws,
                              size_t ws_size, hipStream_t stream) {
  const float* input = (const float*)d_in[0];
  const int* target = (const int*)d_in[1];
  float* ws = (float*)d_ws;
  float* out = (float*)d_out;

  const bool big_ws = ws_size >= (size_t)(WS_PART + NPART_L) * 4;
  const bool mid_ws = ws_size >= (size_t)WS_PART * 4;
  const int partmode = big_ws ? 1 : 0;
  const int hmode = mid_ws ? 1 : 0;
  if (!big_ws || !mid_ws) {
    hipMemsetAsync(ws, 0, 2180 * sizeof(float), stream);
  }
  if (big_ws) {
    // Read-BW probe: canonical contiguous pattern; output is dead storage
    // (pass1 overwrites every slot it writes before reduce1 reads).
    probe<<<PROBE_BLOCKS, 256, 0, stream>>>(input, ws);
  }
  dim3 grid1(P1_BLOCKS, N_IMG);
  pass1<<<grid1, 256, 0, stream>>>(input, target, ws, partmode);
  if (big_ws) {
    dim3 gridr(17, N_IMG);
    reduce1<<<gridr, 256, 0, stream>>>(ws);
  }
  dim3 grid2(BLOCKS2_X, N_IMG);
  pass2<<<grid2, 256, 0, stream>>>(input, target, ws, hmode);
  finalize<<<1, 256, 0, stream>>>(ws, out, hmode);
}